// Round 8
// baseline (1560.867 us; speedup 1.0000x reference)
//
#include <hip/hip_runtime.h>
#include <hip/hip_bf16.h>

static constexpr int kB = 4;
static constexpr int kT = 1024;
static constexpr int kIn = 172;
static constexpr int kD = 512;
static constexpr int kH = 8;
static constexpr int kHD = 64;
static constexpr int kFF = 2048;
static constexpr int kNCLS = 1296;
static constexpr float kEps = 1e-5f;

typedef __attribute__((ext_vector_type(8))) short bf16x8_t;
typedef __attribute__((ext_vector_type(4))) float f32x4_t;
typedef __attribute__((ext_vector_type(8))) unsigned short u16x8_t;
typedef __attribute__((ext_vector_type(4))) unsigned short u16x4_t;

// round-to-nearest-even f32 -> bf16 bits (finite inputs)
static __device__ __forceinline__ unsigned short f2bf(float f) {
  unsigned int u = __float_as_uint(f);
  unsigned int r = (u + 0x7fffu + ((u >> 16) & 1u)) >> 16;
  return (unsigned short)r;
}

// ---------- f32 -> bf16 bulk convert (n % 8 == 0) ----------
__global__ void cvt_kernel(const float* __restrict__ src, ushort* __restrict__ dst, int n8)
{
  const int i = blockIdx.x * 256 + threadIdx.x;
  if (i >= n8) return;
  const float4 a = *(const float4*)&src[i * 8];
  const float4 b = *(const float4*)&src[i * 8 + 4];
  u16x8_t t;
  t[0] = f2bf(a.x); t[1] = f2bf(a.y); t[2] = f2bf(a.z); t[3] = f2bf(a.w);
  t[4] = f2bf(b.x); t[5] = f2bf(b.y); t[6] = f2bf(b.z); t[7] = f2bf(b.w);
  *(u16x8_t*)&dst[i * 8] = t;
}

// ================= bf16 MFMA GEMM, m97 structure =================
// C[m,n] = sum_k A[m,k]*W[n,k] + bias[n] (+relu) (+resid f32); C f32 and/or Cb bf16.
// Wave tile = MR*16 x NR*16; block = 2x2 waves -> BM=MR*32, BN=NR*32; BK=32.
// LDS linear [row][32], staged via global_load_lds width=16 (wave-uniform base + lane*16).
// Requires M%BM==0, N%BN==0, K%32==0, 16B-aligned A/W rows (K%8==0).
template<int MR, int NR>
__global__ __launch_bounds__(256) void bgemm_kernel(
    const ushort* __restrict__ A, const ushort* __restrict__ W,
    const float* __restrict__ bias, const float* __restrict__ resid,
    float* __restrict__ C, ushort* __restrict__ Cb, int M, int N, int K, int doRelu)
{
  constexpr int BM = MR * 32, BN = NR * 32, BK = 32;
  constexpr int AI = BM / 64;          // gload instrs per wave for A (16 rows each)
  constexpr int BI = BN / 64;
  __shared__ ushort As[BM * BK];
  __shared__ ushort Bs[BN * BK];

  const int tid = threadIdx.x;
  int bid = blockIdx.y * gridDim.x + blockIdx.x;
  const int nwg = gridDim.x * gridDim.y;
  if ((nwg & 7) == 0) bid = (bid & 7) * (nwg >> 3) + (bid >> 3);   // XCD swizzle
  const int bm = (bid / gridDim.x) * BM, bn = (bid % gridDim.x) * BN;

  const int wv = tid >> 6, lane = tid & 63;
  const int lr = lane & 15, lg = lane >> 4;
  const int wr = wv >> 1, wc = wv & 1;

  const int arow0 = wv * (BM / 4);     // wave's staging row range in A tile
  const int brow0 = wv * (BN / 4);
  const int lrow = lane >> 2;          // row within 16-row group
  const int lchunk = (lane & 3) * 8;   // 8 ushorts = 16 B

  f32x4_t acc[MR][NR];
#pragma unroll
  for (int m = 0; m < MR; ++m)
#pragma unroll
    for (int n = 0; n < NR; ++n) acc[m][n] = (f32x4_t){0.f, 0.f, 0.f, 0.f};

  auto stage = [&](int k0) {
#pragma unroll
    for (int i = 0; i < AI; ++i) {
      const ushort* g = A + (size_t)(bm + arow0 + i * 16 + lrow) * K + k0 + lchunk;
      __builtin_amdgcn_global_load_lds(
          (const __attribute__((address_space(1))) void*)g,
          (__attribute__((address_space(3))) void*)&As[(arow0 + i * 16) * BK], 16, 0, 0);
    }
#pragma unroll
    for (int i = 0; i < BI; ++i) {
      const ushort* g = W + (size_t)(bn + brow0 + i * 16 + lrow) * K + k0 + lchunk;
      __builtin_amdgcn_global_load_lds(
          (const __attribute__((address_space(1))) void*)g,
          (__attribute__((address_space(3))) void*)&Bs[(brow0 + i * 16) * BK], 16, 0, 0);
    }
  };

  stage(0);
  const int nsteps = K >> 5;
  for (int s = 0; s < nsteps; ++s) {
    __syncthreads();   // drains vmcnt (compiler) -> staged tile visible
    bf16x8_t af[MR], bf[NR];
#pragma unroll
    for (int m = 0; m < MR; ++m)
      af[m] = *(const bf16x8_t*)&As[(wr * MR * 16 + m * 16 + lr) * BK + lg * 8];
#pragma unroll
    for (int n = 0; n < NR; ++n)
      bf[n] = *(const bf16x8_t*)&Bs[(wc * NR * 16 + n * 16 + lr) * BK + lg * 8];
#pragma unroll
    for (int n = 0; n < NR; ++n)
#pragma unroll
      for (int m = 0; m < MR; ++m)
        acc[m][n] = __builtin_amdgcn_mfma_f32_16x16x32_bf16(af[m], bf[n], acc[m][n], 0, 0, 0);
    __syncthreads();   // compute done before overwrite
    if (s + 1 < nsteps) stage((s + 1) << 5);
  }

  // epilogue: D row = lg*4+v, col = lr (verified mapping)
#pragma unroll
  for (int m = 0; m < MR; ++m) {
#pragma unroll
    for (int v = 0; v < 4; ++v) {
      const int mm = bm + wr * MR * 16 + m * 16 + lg * 4 + v;
#pragma unroll
      for (int n = 0; n < NR; ++n) {
        const int nn = bn + wc * NR * 16 + n * 16 + lr;
        float val = acc[m][n][v] + bias[nn];
        if (doRelu) val = fmaxf(val, 0.f);
        if (resid) val += resid[(size_t)mm * N + nn];
        if (C)  C[(size_t)mm * N + nn] = val;
        if (Cb) Cb[(size_t)mm * N + nn] = f2bf(val);
      }
    }
  }
}

// ================= legacy f32 GEMM (embed K=172, fc1, fc2 N=1296) =================
#define GBM 64
#define GBN 64
#define GBK 16
#define LDST 68

__global__ __launch_bounds__(256) void gemm_kernel(
    const float* __restrict__ A, const float* __restrict__ W,
    const float* __restrict__ bias, const float* __restrict__ resid,
    float* __restrict__ C, int M, int N, int K, int doRelu)
{
  __shared__ __align__(16) float As[GBK][LDST];
  __shared__ __align__(16) float Ws[GBK][LDST];
  const int tid = threadIdx.x;
  const int bm = blockIdx.y * GBM;
  const int bn = blockIdx.x * GBN;
  const int tx = tid & 15, ty = tid >> 4;
  const int li = tid >> 2;
  const int lk = (tid & 3) << 2;

  float acc[4][4];
#pragma unroll
  for (int i = 0; i < 4; ++i)
#pragma unroll
    for (int j = 0; j < 4; ++j) acc[i][j] = 0.f;

  for (int k0 = 0; k0 < K; k0 += GBK) {
    float4 av = make_float4(0.f, 0.f, 0.f, 0.f);
    float4 wv = make_float4(0.f, 0.f, 0.f, 0.f);
    {
      const int m = bm + li;
      if (m < M) {
        if (k0 + lk + 4 <= K) {
          av = *(const float4*)&A[(size_t)m * K + k0 + lk];
        } else {
          float t4[4] = {0.f, 0.f, 0.f, 0.f};
          for (int c = 0; c < 4; ++c) { int k = k0 + lk + c; if (k < K) t4[c] = A[(size_t)m * K + k]; }
          av = make_float4(t4[0], t4[1], t4[2], t4[3]);
        }
      }
      const int n = bn + li;
      if (n < N) {
        if (k0 + lk + 4 <= K) {
          wv = *(const float4*)&W[(size_t)n * K + k0 + lk];
        } else {
          float t4[4] = {0.f, 0.f, 0.f, 0.f};
          for (int c = 0; c < 4; ++c) { int k = k0 + lk + c; if (k < K) t4[c] = W[(size_t)n * K + k]; }
          wv = make_float4(t4[0], t4[1], t4[2], t4[3]);
        }
      }
    }
    __syncthreads();
    As[lk + 0][li] = av.x; As[lk + 1][li] = av.y; As[lk + 2][li] = av.z; As[lk + 3][li] = av.w;
    Ws[lk + 0][li] = wv.x; Ws[lk + 1][li] = wv.y; Ws[lk + 2][li] = wv.z; Ws[lk + 3][li] = wv.w;
    __syncthreads();
#pragma unroll
    for (int kk = 0; kk < GBK; ++kk) {
      const float4 a4 = *(const float4*)&As[kk][ty << 2];
      const float4 b4 = *(const float4*)&Ws[kk][tx << 2];
      const float a[4] = {a4.x, a4.y, a4.z, a4.w};
      const float b[4] = {b4.x, b4.y, b4.z, b4.w};
#pragma unroll
      for (int i = 0; i < 4; ++i)
#pragma unroll
        for (int j = 0; j < 4; ++j) acc[i][j] = fmaf(a[i], b[j], acc[i][j]);
    }
  }

#pragma unroll
  for (int i = 0; i < 4; ++i) {
    const int m = bm + (ty << 2) + i;
    if (m >= M) continue;
#pragma unroll
    for (int j = 0; j < 4; ++j) {
      const int n = bn + (tx << 2) + j;
      if (n >= N) continue;
      float v = acc[i][j] + bias[n];
      if (doRelu) v = fmaxf(v, 0.f);
      if (resid) v += resid[(size_t)m * N + n];
      C[(size_t)m * N + n] = v;
    }
  }
}

// ---------- LayerNorm (f32 in-place + bf16 copy, optional skip-add/skip-save) ----------
__global__ __launch_bounds__(256) void ln_kernel(
    float* __restrict__ X, ushort* __restrict__ Xb,
    const float* __restrict__ g, const float* __restrict__ bta,
    const float* Padd, float* Pout)
{
  const int row = blockIdx.x;
  const int tid = threadIdx.x;
  float* xr = X + (size_t)row * kD;
  const float x0 = xr[tid];
  const float x1 = xr[tid + 256];
  float s = x0 + x1;
  float q = x0 * x0 + x1 * x1;
#pragma unroll
  for (int off = 32; off > 0; off >>= 1) {
    s += __shfl_down(s, off);
    q += __shfl_down(q, off);
  }
  __shared__ float ss[4], qq[4];
  const int w = tid >> 6;
  if ((tid & 63) == 0) { ss[w] = s; qq[w] = q; }
  __syncthreads();
  const float S = ss[0] + ss[1] + ss[2] + ss[3];
  const float Q = qq[0] + qq[1] + qq[2] + qq[3];
  const float mean = S * (1.f / kD);
  const float var = Q * (1.f / kD) - mean * mean;
  const float inv = rsqrtf(var + kEps);
  float v0 = (x0 - mean) * inv * g[tid] + bta[tid];
  float v1 = (x1 - mean) * inv * g[tid + 256] + bta[tid + 256];
  if (Padd) {
    v0 += Padd[(size_t)row * kD + tid];
    v1 += Padd[(size_t)row * kD + tid + 256];
  }
  xr[tid] = v0; xr[tid + 256] = v1;
  ushort* xb = Xb + (size_t)row * kD;
  xb[tid] = f2bf(v0); xb[tid + 256] = f2bf(v1);
  if (Pout) {
    Pout[(size_t)row * kD + tid] = v0;
    Pout[(size_t)row * kD + tid + 256] = v1;
  }
}

// ---------- MFMA flash attention (bf16 qkv in/out, f32 softmax/accum) ----------
// async-STAGE split: next tile's K/V global loads issue right after the staging
// barrier, so HBM/L2 latency hides under QK^T + softmax + PV of the current tile.
#define KSTR 72   // K/V LDS row stride (ushort)
#define PSTR 74   // P LDS row stride (odd dword stride -> ~2-way write banks)
__global__ __launch_bounds__(256) void attn_mfma_kernel(
    const ushort* __restrict__ qkv, ushort* __restrict__ O)
{
  const int b = blockIdx.z, h = blockIdx.y;
  const int q0 = blockIdx.x << 6;
  const int tid = threadIdx.x;
  const int wv = tid >> 6, lane = tid & 63;
  const int lr = lane & 15;
  const int lg = lane >> 4;

  __shared__ ushort Ks[64 * KSTR];
  __shared__ ushort Vt[64 * KSTR];
  __shared__ ushort Pl[4][16 * PSTR];

  bf16x8_t qa[2];
  {
    const ushort* qrow = qkv + ((size_t)(b * kT + q0 + wv * 16 + lr)) * (3 * kD) + h * kHD + lg * 8;
    qa[0] = *(const bf16x8_t*)qrow;
    qa[1] = *(const bf16x8_t*)(qrow + 32);
  }

  float m_[4], l_[4];
  f32x4_t oacc[4];
#pragma unroll
  for (int r = 0; r < 4; ++r) { m_[r] = -1e30f; l_[r] = 0.f; }
#pragma unroll
  for (int nb = 0; nb < 4; ++nb) oacc[nb] = (f32x4_t){0.f, 0.f, 0.f, 0.f};

  const int srow = tid >> 2;          // K staging: key row 0..63
  const int sd   = (tid & 3) << 4;    // K staging: d offset 0,16,32,48
  const int vkp  = tid & 31;          // V staging: key pair (keys 2vkp, 2vkp+1)
  const int vdh  = tid >> 5;          // V staging: d octet

  u16x8_t k0_, k1_, v0_, v1_;
  auto load_regs = [&](int kt) {
    const ushort* kr = qkv + ((size_t)(b * kT + (kt << 6) + srow)) * (3 * kD) + kD + h * kHD + sd;
    k0_ = *(const u16x8_t*)kr;
    k1_ = *(const u16x8_t*)(kr + 8);
    const ushort* vr = qkv + ((size_t)(b * kT + (kt << 6) + 2 * vkp)) * (3 * kD) + 2 * kD + h * kHD + vdh * 8;
    v0_ = *(const u16x8_t*)vr;
    v1_ = *(const u16x8_t*)(vr + 3 * kD);
  };

  load_regs(0);
  for (int kt = 0; kt < kT / 64; ++kt) {
    __syncthreads();   // previous compute done -> LDS free to overwrite
    {
      *(u16x8_t*)&Ks[srow * KSTR + sd]     = k0_;
      *(u16x8_t*)&Ks[srow * KSTR + sd + 8] = k1_;
#pragma unroll
      for (int e = 0; e < 8; ++e) {
        const unsigned int packv = (unsigned int)v0_[e] | ((unsigned int)v1_[e] << 16);
        *(unsigned int*)&Vt[(vdh * 8 + e) * KSTR + 2 * vkp] = packv;
      }
    }
    __syncthreads();   // staged tile visible
    if (kt + 1 < kT / 64) load_regs(kt + 1);   // issue early; hides under compute

    f32x4_t s[4];
#pragma unroll
    for (int cc = 0; cc < 4; ++cc) {
      const ushort* kb = &Ks[(cc * 16 + lr) * KSTR + lg * 8];
      const bf16x8_t kf0 = *(const bf16x8_t*)kb;
      const bf16x8_t kf1 = *(const bf16x8_t*)(kb + 32);
      f32x4_t acc = (f32x4_t){0.f, 0.f, 0.f, 0.f};
      acc = __builtin_amdgcn_mfma_f32_16x16x32_bf16(qa[0], kf0, acc, 0, 0, 0);
      acc = __builtin_amdgcn_mfma_f32_16x16x32_bf16(qa[1], kf1, acc, 0, 0, 0);
#pragma unroll
      for (int r = 0; r < 4; ++r) acc[r] *= 0.125f;
      s[cc] = acc;
    }

#pragma unroll
    for (int r = 0; r < 4; ++r) {
      float mx = fmaxf(fmaxf(s[0][r], s[1][r]), fmaxf(s[2][r], s[3][r]));
      mx = fmaxf(mx, __shfl_xor(mx, 1));
      mx = fmaxf(mx, __shfl_xor(mx, 2));
      mx = fmaxf(mx, __shfl_xor(mx, 4));
      mx = fmaxf(mx, __shfl_xor(mx, 8));
      const float mnew = fmaxf(m_[r], mx);
      const float alpha = __expf(m_[r] - mnew);
      float sum = 0.f;
#pragma unroll
      for (int cc = 0; cc < 4; ++cc) {
        const float p = __expf(s[cc][r] - mnew);
        s[cc][r] = p;
        sum += p;
      }
      sum += __shfl_xor(sum, 1);
      sum += __shfl_xor(sum, 2);
      sum += __shfl_xor(sum, 4);
      sum += __shfl_xor(sum, 8);
      l_[r] = l_[r] * alpha + sum;
      m_[r] = mnew;
#pragma unroll
      for (int nb = 0; nb < 4; ++nb) oacc[nb][r] *= alpha;
#pragma unroll
      for (int cc = 0; cc < 4; ++cc)
        Pl[wv][(lg * 4 + r) * PSTR + cc * 16 + lr] = f2bf(s[cc][r]);
    }

    const bf16x8_t pa0 = *(const bf16x8_t*)&Pl[wv][lr * PSTR + lg * 8];
    const bf16x8_t pa1 = *(const bf16x8_t*)&Pl[wv][lr * PSTR + 32 + lg * 8];
#pragma unroll
    for (int nb = 0; nb < 4; ++nb) {
      const ushort* vb = &Vt[(nb * 16 + lr) * KSTR + lg * 8];
      const bf16x8_t vf0 = *(const bf16x8_t*)vb;
      const bf16x8_t vf1 = *(const bf16x8_t*)(vb + 32);
      oacc[nb] = __builtin_amdgcn_mfma_f32_16x16x32_bf16(pa0, vf0, oacc[nb], 0, 0, 0);
      oacc[nb] = __builtin_amdgcn_mfma_f32_16x16x32_bf16(pa1, vf1, oacc[nb], 0, 0, 0);
    }
  }

#pragma unroll
  for (int nb = 0; nb < 4; ++nb) {
#pragma unroll
    for (int r = 0; r < 4; ++r) {
      const int row = lg * 4 + r;
      const int col = nb * 16 + lr;
      O[((size_t)(b * kT + q0 + wv * 16 + row)) * kD + h * kHD + col] = f2bf(oacc[nb][r] / l_[r]);
    }
  }
}

// ---------- positional encoding add (f32 + bf16 copy) ----------
__global__ __launch_bounds__(256) void posenc_kernel(float* __restrict__ X, ushort* __restrict__ Xb)
{
  const int bt = blockIdx.x;
  const int t = bt & (kT - 1);
  float* row = X + (size_t)bt * kD;
  ushort* rb = Xb + (size_t)bt * kD;
#pragma unroll
  for (int p = 0; p < 2; ++p) {
    const int d = threadIdx.x + p * 256;
    const int j = d >> 1;
    const float inv = expf(-(float)j * 0.03597789207803197f);  // ln(10000)/256
    const float ang = (float)t * inv;
    const float pe = (d & 1) ? cosf(ang) : sinf(ang);
    const float v = row[d] + pe;
    row[d] = v;
    rb[d] = f2bf(v);
  }
}

// ---------- fused avgpool + im2col (bf16 out) ----------
__global__ void im2col_pool_kernel(const float* __restrict__ X, ushort* __restrict__ X5,
                                   int Tt, int n4)
{
  const int idx = blockIdx.x * 256 + threadIdx.x;
  if (idx >= n4) return;
  const int ci4 = idx & 127;
  int r = idx >> 7;
  const int tap = r % 5; r /= 5;
  const int t = r % Tt;
  const int b = r / Tt;
  const int ts = t + tap - 2;
  u16x4_t o = (u16x4_t){0, 0, 0, 0};
  if (ts >= 0 && ts < Tt) {
    const float* p = X + ((size_t)(b * 2 * Tt + 2 * ts)) * kD + ci4 * 4;
    const float4 x0 = *(const float4*)p;
    const float4 x1 = *(const float4*)(p + kD);
    o[0] = f2bf(0.5f * (x0.x + x1.x)); o[1] = f2bf(0.5f * (x0.y + x1.y));
    o[2] = f2bf(0.5f * (x0.z + x1.z)); o[3] = f2bf(0.5f * (x0.w + x1.w));
  }
  *(u16x4_t*)&X5[((size_t)(b * Tt + t)) * 2560 + tap * kD + ci4 * 4] = o;
}

// conv weight transpose -> bf16: Wt[co][tap*512+ci] = w[co][ci][tap]
__global__ void convw_t_kernel(const float* __restrict__ w, ushort* __restrict__ Wt)
{
  const int idx = blockIdx.x * 256 + threadIdx.x;
  if (idx >= 512 * 512 * 5) return;
  const int ci = idx & 511;
  int r = idx >> 9;
  const int tap = r % 5;
  const int co = r / 5;
  Wt[(size_t)co * 2560 + tap * 512 + ci] = f2bf(w[(size_t)co * 2560 + ci * 5 + tap]);
}

extern "C" void kernel_launch(void* const* d_in, const int* in_sizes, int n_in,
                              void* d_out, int out_size, void* d_ws, size_t ws_size,
                              hipStream_t stream)
{
  (void)in_sizes; (void)n_in; (void)out_size;
  const float* poses  = (const float*)d_in[0];
  const float* pose_w = (const float*)d_in[1];
  const float* pose_b = (const float*)d_in[2];
  const float* in_w   = (const float*)d_in[3];
  const float* in_b   = (const float*)d_in[4];
  const float* out_w  = (const float*)d_in[5];
  const float* out_b  = (const float*)d_in[6];
  const float* ln1_g  = (const float*)d_in[7];
  const float* ln1_b  = (const float*)d_in[8];
  const float* ffn_w1 = (const float*)d_in[9];
  const float* ffn_b1 = (const float*)d_in[10];
  const float* ffn_w2 = (const float*)d_in[11];
  const float* ffn_b2 = (const float*)d_in[12];
  const float* ln2_g  = (const float*)d_in[13];
  const float* ln2_b  = (const float*)d_in[14];
  const float* tcn1_w = (const float*)d_in[15];
  const float* tcn1_b = (const float*)d_in[16];
  const float* tcn2_w = (const float*)d_in[17];
  const float* tcn2_b = (const float*)d_in[18];
  const float* fc1_w  = (const float*)d_in[19];
  const float* fc1_b  = (const float*)d_in[20];
  const float* fc2_w  = (const float*)d_in[21];
  const float* fc2_b  = (const float*)d_in[22];

  // ---- workspace layout (byte offsets) ----
  char* base = (char*)d_ws;
  float*  A    = (float*)(base);
  float*  Y    = (float*)(base + 8388608);
  float*  P    = (float*)(base + 16777216);
  ushort* Abf  = (ushort*)(base + 25165824);
  ushort* QKV  = (ushort*)(base + 29360128);   // 6M ushort
  ushort* Ybf  = QKV;                          // lifetime-disjoint alias
  ushort* X5   = QKV;                          // head phase
  ushort* MID  = (ushort*)(base + 41943040);   // 8M ushort
  ushort* ATTb = MID;                          // lifetime-disjoint alias
  ushort* CW   = MID;                          // head phase
  ushort* Wbf  = (ushort*)(base + 58720256);

  // per-layer weight element counts
  const size_t nWq = (size_t)3 * kD * kD;      // 786432
  const size_t nWo = (size_t)kD * kD;          // 262144
  const size_t nW1 = (size_t)kFF * kD;         // 1048576
  const size_t nW2 = (size_t)kD * kFF;         // 1048576
  const size_t nWl = nWq + nWo + nW1 + nW2;    // 3145728
  const bool fullW = ws_size >= (size_t)58720256 + nWl * 8 * 2;

  const int M = kB * kT;  // 4096
  dim3 blk(256);
  auto cvt = [&](const float* s, ushort* d, size_t n) {
    cvt_kernel<<<(int)((n / 8 + 255) / 256), blk, 0, stream>>>(s, d, (int)(n / 8));
  };

  if (fullW) {   // one-time per launch: convert all transformer weights
    cvt(in_w,   Wbf,                        nWq * 8);
    cvt(out_w,  Wbf + nWq * 8,              nWo * 8);
    cvt(ffn_w1, Wbf + nWq * 8 + nWo * 8,    nW1 * 8);
    cvt(ffn_w2, Wbf + (nWq + nWo + nW1) * 8, nW2 * 8);
  }

  // embed: A = poses @ pose_w.T + pose_b ; += posenc (writes A + Abf)
  gemm_kernel<<<dim3(kD / GBN, M / GBM), blk, 0, stream>>>(poses, pose_w, pose_b, nullptr, A, M, kD, kIn, 0);
  posenc_kernel<<<M, blk, 0, stream>>>(A, Abf);

  for (int l = 0; l < 8; ++l) {
    const ushort *Wq, *Wo, *W1, *W2;
    if (fullW) {
      Wq = Wbf + (size_t)l * nWq;
      Wo = Wbf + nWq * 8 + (size_t)l * nWo;
      W1 = Wbf + nWq * 8 + nWo * 8 + (size_t)l * nW1;
      W2 = Wbf + (nWq + nWo + nW1) * 8 + (size_t)l * nW2;
    } else {   // rotate: convert this layer's weights into Wbf
      cvt(in_w   + (size_t)l * nWq, Wbf, nWq);
      cvt(out_w  + (size_t)l * nWo, Wbf + nWq, nWo);
      cvt(ffn_w1 + (size_t)l * nW1, Wbf + nWq + nWo, nW1);
      cvt(ffn_w2 + (size_t)l * nW2, Wbf + nWq + nWo + nW1, nW2);
      Wq = Wbf; Wo = Wbf + nWq; W1 = Wbf + nWq + nWo; W2 = Wbf + nWq + nWo + nW1;
    }

    // qkv (bf16 out only), 128x128 tile
    bgemm_kernel<4, 4><<<dim3(3 * kD / 128, M / 128), blk, 0, stream>>>(
        Abf, Wq, in_b + (size_t)l * 3 * kD, nullptr, nullptr, QKV, M, 3 * kD, kD, 0);
    // attention (bf16 in/out)
    attn_mfma_kernel<<<dim3(kT / 64, kH, kB), blk, 0, stream>>>(QKV, ATTb);
    // out-proj: Y = ATTb @ Wo + b + A (f32 out), 128x64 tile (N=512 -> 256 blocks)
    bgemm_kernel<4, 2><<<dim3(kD / 64, M / 128), blk, 0, stream>>>(
        ATTb, Wo, out_b + (size_t)l * kD, A, Y, nullptr, M, kD, kD, 0);
    ln_kernel<<<M, blk, 0, stream>>>(Y, Ybf, ln1_g + (size_t)l * kD, ln1_b + (size_t)l * kD,
                                     nullptr, nullptr);
    // ffn1: MID = relu(Ybf @ W1 + b), 128x128 tile
    bgemm_kernel<4, 4><<<dim3(kFF / 128, M / 128), blk, 0, stream>>>(
        Ybf, W1, ffn_b1 + (size_t)l * kFF, nullptr, nullptr, MID, M, kFF, kD, 1);
    // ffn2: A = MID @ W2 + b + Y (f32 out), 128x64 tile
    bgemm_kernel<4, 2><<<dim3(kD / 64, M / 128), blk, 0, stream>>>(
        MID, W2, ffn_b2 + (size_t)l * kD, Y, A, nullptr, M, kD, kFF, 0);
    // ln2, fused with skip-stream: add P after LN (l=3,5,7), snapshot P (l=1,3,5)
    {
      const float* padd = (l == 3 || l == 5 || l == 7) ? P : nullptr;
      float* pout = (l == 1 || l == 3 || l == 5) ? P : nullptr;
      ln_kernel<<<M, blk, 0, stream>>>(A, Abf, ln2_g + (size_t)l * kD, ln2_b + (size_t)l * kD,
                                       padd, pout);
    }
  }

  // head: pool+conv1 -> pool+conv2 -> fc1 -> fc2
  {
    const int T1 = kT / 2;   // 512
    const int T2 = kT / 4;   // 256
    convw_t_kernel<<<(512 * 512 * 5 + 255) / 256, blk, 0, stream>>>(tcn1_w, CW);
    const int n4a = kB * T1 * 5 * (kD / 4);
    im2col_pool_kernel<<<(n4a + 255) / 256, blk, 0, stream>>>(A, X5, T1, n4a);
    bgemm_kernel<4, 2><<<dim3(kD / 64, kB * T1 / 128), blk, 0, stream>>>(
        X5, CW, tcn1_b, nullptr, Y, nullptr, kB * T1, kD, 2560, 0);
    convw_t_kernel<<<(512 * 512 * 5 + 255) / 256, blk, 0, stream>>>(tcn2_w, CW);
    const int n4b = kB * T2 * 5 * (kD / 4);
    im2col_pool_kernel<<<(n4b + 255) / 256, blk, 0, stream>>>(Y, X5, T2, n4b);
    bgemm_kernel<4, 2><<<dim3(kD / 64, kB * T2 / 128), blk, 0, stream>>>(
        X5, CW, tcn2_b, nullptr, A, nullptr, kB * T2, kD, 2560, 0);
    const int Mh = kB * T2;  // 1024
    gemm_kernel<<<dim3(128 / GBN, Mh / GBM), blk, 0, stream>>>(A, fc1_w, fc1_b, nullptr, Y, Mh, 128, kD, 0);
    gemm_kernel<<<dim3((kNCLS + GBN - 1) / GBN, Mh / GBM), blk, 0, stream>>>(
        Y, fc2_w, fc2_b, nullptr, (float*)d_out, Mh, kNCLS, 128, 0);
  }
}

// Round 9
// 1281.277 us; speedup vs baseline: 1.2182x; 1.2182x over previous
//
#include <hip/hip_runtime.h>
#include <hip/hip_bf16.h>

static constexpr int kB = 4;
static constexpr int kT = 1024;
static constexpr int kIn = 172;
static constexpr int kD = 512;
static constexpr int kH = 8;
static constexpr int kHD = 64;
static constexpr int kFF = 2048;
static constexpr int kNCLS = 1296;
static constexpr float kEps = 1e-5f;

typedef __attribute__((ext_vector_type(8))) short bf16x8_t;
typedef __attribute__((ext_vector_type(4))) float f32x4_t;
typedef __attribute__((ext_vector_type(8))) unsigned short u16x8_t;
typedef __attribute__((ext_vector_type(4))) unsigned short u16x4_t;

// round-to-nearest-even f32 -> bf16 bits (finite inputs)
static __device__ __forceinline__ unsigned short f2bf(float f) {
  unsigned int u = __float_as_uint(f);
  unsigned int r = (u + 0x7fffu + ((u >> 16) & 1u)) >> 16;
  return (unsigned short)r;
}

// ---------- f32 -> bf16 bulk convert (n % 8 == 0) ----------
__global__ void cvt_kernel(const float* __restrict__ src, ushort* __restrict__ dst, int n8)
{
  const int i = blockIdx.x * 256 + threadIdx.x;
  if (i >= n8) return;
  const float4 a = *(const float4*)&src[i * 8];
  const float4 b = *(const float4*)&src[i * 8 + 4];
  u16x8_t t;
  t[0] = f2bf(a.x); t[1] = f2bf(a.y); t[2] = f2bf(a.z); t[3] = f2bf(a.w);
  t[4] = f2bf(b.x); t[5] = f2bf(b.y); t[6] = f2bf(b.z); t[7] = f2bf(b.w);
  *(u16x8_t*)&dst[i * 8] = t;
}

// ================= bf16 MFMA GEMM (8-wave, BK=64, reg-prefetch) =================
// C[m,n] = sum_k A[m,k]*W[n,k] + bias[n] (+relu) (+resid f32); C f32 and/or Cb bf16.
// WM x WN waves (block = WM*WN*64 threads); wave tile = MR*16 x NR*16;
// BM = MR*16*WM, BN = NR*16*WN, BK = 64. LDS rows padded to 72 ushorts (2-way banks).
// Requires M%BM==0, N%BN==0, K%64==0.
template<int MR, int NR, int WM, int WN>
__global__ __launch_bounds__(WM * WN * 64) void bgemm_kernel(
    const ushort* __restrict__ A, const ushort* __restrict__ W,
    const float* __restrict__ bias, const float* __restrict__ resid,
    float* __restrict__ C, ushort* __restrict__ Cb, int M, int N, int K, int doRelu)
{
  constexpr int THREADS = WM * WN * 64;
  constexpr int BM = MR * 16 * WM, BN = NR * 16 * WN;
  constexpr int SRD = 72;
  constexpr int TPRA = THREADS / BM, CSA = 64 / TPRA, NLA = CSA / 8;
  constexpr int TPRB = THREADS / BN, CSB = 64 / TPRB, NLB = CSB / 8;
  __shared__ ushort As[BM * SRD];
  __shared__ ushort Bs[BN * SRD];

  const int tid = threadIdx.x;
  int bid = blockIdx.y * gridDim.x + blockIdx.x;
  const int nwg = gridDim.x * gridDim.y;
  if ((nwg & 7) == 0) bid = (bid & 7) * (nwg >> 3) + (bid >> 3);   // XCD swizzle
  const int bm = (bid / gridDim.x) * BM, bn = (bid % gridDim.x) * BN;

  const int wv = tid >> 6, lane = tid & 63;
  const int lr = lane & 15, lg = lane >> 4;
  const int wr = wv / WN, wc = wv % WN;

  const int ra = tid / TPRA, ca = (tid % TPRA) * CSA;
  const int rb = tid / TPRB, cb = (tid % TPRB) * CSB;

  f32x4_t acc[MR][NR];
#pragma unroll
  for (int m = 0; m < MR; ++m)
#pragma unroll
    for (int n = 0; n < NR; ++n) acc[m][n] = (f32x4_t){0.f, 0.f, 0.f, 0.f};

  u16x8_t pa[NLA], pb[NLB];
  auto loadAB = [&](int k0) {
    const ushort* ap = A + (size_t)(bm + ra) * K + k0 + ca;
#pragma unroll
    for (int j = 0; j < NLA; ++j) pa[j] = *(const u16x8_t*)(ap + j * 8);
    const ushort* bp = W + (size_t)(bn + rb) * K + k0 + cb;
#pragma unroll
    for (int j = 0; j < NLB; ++j) pb[j] = *(const u16x8_t*)(bp + j * 8);
  };
  auto storeLDS = [&]() {
#pragma unroll
    for (int j = 0; j < NLA; ++j) *(u16x8_t*)&As[ra * SRD + ca + j * 8] = pa[j];
#pragma unroll
    for (int j = 0; j < NLB; ++j) *(u16x8_t*)&Bs[rb * SRD + cb + j * 8] = pb[j];
  };

  loadAB(0);
  storeLDS();
  __syncthreads();

  const int nsteps = K >> 6;
  for (int s = 0; s < nsteps; ++s) {
    const bool more = (s + 1) < nsteps;
    if (more) loadAB((s + 1) << 6);   // prefetch overlaps MFMA

#pragma unroll
    for (int kk = 0; kk < 2; ++kk) {
      bf16x8_t af[MR];
#pragma unroll
      for (int m = 0; m < MR; ++m)
        af[m] = *(const bf16x8_t*)&As[(wr * MR * 16 + m * 16 + lr) * SRD + kk * 32 + lg * 8];
#pragma unroll
      for (int n = 0; n < NR; ++n) {
        const bf16x8_t bf = *(const bf16x8_t*)&Bs[(wc * NR * 16 + n * 16 + lr) * SRD + kk * 32 + lg * 8];
#pragma unroll
        for (int m = 0; m < MR; ++m)
          acc[m][n] = __builtin_amdgcn_mfma_f32_16x16x32_bf16(af[m], bf, acc[m][n], 0, 0, 0);
      }
    }
    __syncthreads();
    if (more) { storeLDS(); __syncthreads(); }
  }

  // epilogue: D row = lg*4+v, col = lr (verified mapping)
#pragma unroll
  for (int m = 0; m < MR; ++m) {
#pragma unroll
    for (int v = 0; v < 4; ++v) {
      const int mm = bm + wr * MR * 16 + m * 16 + lg * 4 + v;
#pragma unroll
      for (int n = 0; n < NR; ++n) {
        const int nn = bn + wc * NR * 16 + n * 16 + lr;
        float val = acc[m][n][v] + bias[nn];
        if (doRelu) val = fmaxf(val, 0.f);
        if (resid) val += resid[(size_t)mm * N + nn];
        if (C)  C[(size_t)mm * N + nn] = val;
        if (Cb) Cb[(size_t)mm * N + nn] = f2bf(val);
      }
    }
  }
}

// ================= legacy f32 GEMM (embed K=172, fc1, fc2 N=1296) =================
#define GBM 64
#define GBN 64
#define GBK 16
#define LDST 68

__global__ __launch_bounds__(256) void gemm_kernel(
    const float* __restrict__ A, const float* __restrict__ W,
    const float* __restrict__ bias, const float* __restrict__ resid,
    float* __restrict__ C, int M, int N, int K, int doRelu)
{
  __shared__ __align__(16) float As[GBK][LDST];
  __shared__ __align__(16) float Ws[GBK][LDST];
  const int tid = threadIdx.x;
  const int bm = blockIdx.y * GBM;
  const int bn = blockIdx.x * GBN;
  const int tx = tid & 15, ty = tid >> 4;
  const int li = tid >> 2;
  const int lk = (tid & 3) << 2;

  float acc[4][4];
#pragma unroll
  for (int i = 0; i < 4; ++i)
#pragma unroll
    for (int j = 0; j < 4; ++j) acc[i][j] = 0.f;

  for (int k0 = 0; k0 < K; k0 += GBK) {
    float4 av = make_float4(0.f, 0.f, 0.f, 0.f);
    float4 wv = make_float4(0.f, 0.f, 0.f, 0.f);
    {
      const int m = bm + li;
      if (m < M) {
        if (k0 + lk + 4 <= K) {
          av = *(const float4*)&A[(size_t)m * K + k0 + lk];
        } else {
          float t4[4] = {0.f, 0.f, 0.f, 0.f};
          for (int c = 0; c < 4; ++c) { int k = k0 + lk + c; if (k < K) t4[c] = A[(size_t)m * K + k]; }
          av = make_float4(t4[0], t4[1], t4[2], t4[3]);
        }
      }
      const int n = bn + li;
      if (n < N) {
        if (k0 + lk + 4 <= K) {
          wv = *(const float4*)&W[(size_t)n * K + k0 + lk];
        } else {
          float t4[4] = {0.f, 0.f, 0.f, 0.f};
          for (int c = 0; c < 4; ++c) { int k = k0 + lk + c; if (k < K) t4[c] = W[(size_t)n * K + k]; }
          wv = make_float4(t4[0], t4[1], t4[2], t4[3]);
        }
      }
    }
    __syncthreads();
    As[lk + 0][li] = av.x; As[lk + 1][li] = av.y; As[lk + 2][li] = av.z; As[lk + 3][li] = av.w;
    Ws[lk + 0][li] = wv.x; Ws[lk + 1][li] = wv.y; Ws[lk + 2][li] = wv.z; Ws[lk + 3][li] = wv.w;
    __syncthreads();
#pragma unroll
    for (int kk = 0; kk < GBK; ++kk) {
      const float4 a4 = *(const float4*)&As[kk][ty << 2];
      const float4 b4 = *(const float4*)&Ws[kk][tx << 2];
      const float a[4] = {a4.x, a4.y, a4.z, a4.w};
      const float b[4] = {b4.x, b4.y, b4.z, b4.w};
#pragma unroll
      for (int i = 0; i < 4; ++i)
#pragma unroll
        for (int j = 0; j < 4; ++j) acc[i][j] = fmaf(a[i], b[j], acc[i][j]);
    }
  }

#pragma unroll
  for (int i = 0; i < 4; ++i) {
    const int m = bm + (ty << 2) + i;
    if (m >= M) continue;
#pragma unroll
    for (int j = 0; j < 4; ++j) {
      const int n = bn + (tx << 2) + j;
      if (n >= N) continue;
      float v = acc[i][j] + bias[n];
      if (doRelu) v = fmaxf(v, 0.f);
      if (resid) v += resid[(size_t)m * N + n];
      C[(size_t)m * N + n] = v;
    }
  }
}

// ---------- LayerNorm (f32 in-place + bf16 copy, optional skip-add/skip-save) ----------
__global__ __launch_bounds__(256) void ln_kernel(
    float* __restrict__ X, ushort* __restrict__ Xb,
    const float* __restrict__ g, const float* __restrict__ bta,
    const float* Padd, float* Pout)
{
  const int row = blockIdx.x;
  const int tid = threadIdx.x;
  float* xr = X + (size_t)row * kD;
  const float x0 = xr[tid];
  const float x1 = xr[tid + 256];
  float s = x0 + x1;
  float q = x0 * x0 + x1 * x1;
#pragma unroll
  for (int off = 32; off > 0; off >>= 1) {
    s += __shfl_down(s, off);
    q += __shfl_down(q, off);
  }
  __shared__ float ss[4], qq[4];
  const int w = tid >> 6;
  if ((tid & 63) == 0) { ss[w] = s; qq[w] = q; }
  __syncthreads();
  const float S = ss[0] + ss[1] + ss[2] + ss[3];
  const float Q = qq[0] + qq[1] + qq[2] + qq[3];
  const float mean = S * (1.f / kD);
  const float var = Q * (1.f / kD) - mean * mean;
  const float inv = rsqrtf(var + kEps);
  float v0 = (x0 - mean) * inv * g[tid] + bta[tid];
  float v1 = (x1 - mean) * inv * g[tid + 256] + bta[tid + 256];
  if (Padd) {
    v0 += Padd[(size_t)row * kD + tid];
    v1 += Padd[(size_t)row * kD + tid + 256];
  }
  xr[tid] = v0; xr[tid + 256] = v1;
  ushort* xb = Xb + (size_t)row * kD;
  xb[tid] = f2bf(v0); xb[tid + 256] = f2bf(v1);
  if (Pout) {
    Pout[(size_t)row * kD + tid] = v0;
    Pout[(size_t)row * kD + tid + 256] = v1;
  }
}

// ---------- MFMA flash attention (bf16 qkv in/out, f32 softmax/accum) ----------
// async-STAGE split: next tile's K/V global loads issue right after the staging
// barrier, so HBM/L2 latency hides under QK^T + softmax + PV of the current tile.
#define KSTR 72   // K/V LDS row stride (ushort)
#define PSTR 74   // P LDS row stride (odd dword stride -> ~2-way write banks)
__global__ __launch_bounds__(256) void attn_mfma_kernel(
    const ushort* __restrict__ qkv, ushort* __restrict__ O)
{
  const int b = blockIdx.z, h = blockIdx.y;
  const int q0 = blockIdx.x << 6;
  const int tid = threadIdx.x;
  const int wv = tid >> 6, lane = tid & 63;
  const int lr = lane & 15;
  const int lg = lane >> 4;

  __shared__ ushort Ks[64 * KSTR];
  __shared__ ushort Vt[64 * KSTR];
  __shared__ ushort Pl[4][16 * PSTR];

  bf16x8_t qa[2];
  {
    const ushort* qrow = qkv + ((size_t)(b * kT + q0 + wv * 16 + lr)) * (3 * kD) + h * kHD + lg * 8;
    qa[0] = *(const bf16x8_t*)qrow;
    qa[1] = *(const bf16x8_t*)(qrow + 32);
  }

  float m_[4], l_[4];
  f32x4_t oacc[4];
#pragma unroll
  for (int r = 0; r < 4; ++r) { m_[r] = -1e30f; l_[r] = 0.f; }
#pragma unroll
  for (int nb = 0; nb < 4; ++nb) oacc[nb] = (f32x4_t){0.f, 0.f, 0.f, 0.f};

  const int srow = tid >> 2;          // K staging: key row 0..63
  const int sd   = (tid & 3) << 4;    // K staging: d offset 0,16,32,48
  const int vkp  = tid & 31;          // V staging: key pair (keys 2vkp, 2vkp+1)
  const int vdh  = tid >> 5;          // V staging: d octet

  u16x8_t k0_, k1_, v0_, v1_;
  auto load_regs = [&](int kt) {
    const ushort* kr = qkv + ((size_t)(b * kT + (kt << 6) + srow)) * (3 * kD) + kD + h * kHD + sd;
    k0_ = *(const u16x8_t*)kr;
    k1_ = *(const u16x8_t*)(kr + 8);
    const ushort* vr = qkv + ((size_t)(b * kT + (kt << 6) + 2 * vkp)) * (3 * kD) + 2 * kD + h * kHD + vdh * 8;
    v0_ = *(const u16x8_t*)vr;
    v1_ = *(const u16x8_t*)(vr + 3 * kD);
  };

  load_regs(0);
  for (int kt = 0; kt < kT / 64; ++kt) {
    __syncthreads();   // previous compute done -> LDS free to overwrite
    {
      *(u16x8_t*)&Ks[srow * KSTR + sd]     = k0_;
      *(u16x8_t*)&Ks[srow * KSTR + sd + 8] = k1_;
#pragma unroll
      for (int e = 0; e < 8; ++e) {
        const unsigned int packv = (unsigned int)v0_[e] | ((unsigned int)v1_[e] << 16);
        *(unsigned int*)&Vt[(vdh * 8 + e) * KSTR + 2 * vkp] = packv;
      }
    }
    __syncthreads();   // staged tile visible
    if (kt + 1 < kT / 64) load_regs(kt + 1);   // issue early; hides under compute

    f32x4_t s[4];
#pragma unroll
    for (int cc = 0; cc < 4; ++cc) {
      const ushort* kb = &Ks[(cc * 16 + lr) * KSTR + lg * 8];
      const bf16x8_t kf0 = *(const bf16x8_t*)kb;
      const bf16x8_t kf1 = *(const bf16x8_t*)(kb + 32);
      f32x4_t acc = (f32x4_t){0.f, 0.f, 0.f, 0.f};
      acc = __builtin_amdgcn_mfma_f32_16x16x32_bf16(qa[0], kf0, acc, 0, 0, 0);
      acc = __builtin_amdgcn_mfma_f32_16x16x32_bf16(qa[1], kf1, acc, 0, 0, 0);
#pragma unroll
      for (int r = 0; r < 4; ++r) acc[r] *= 0.125f;
      s[cc] = acc;
    }

#pragma unroll
    for (int r = 0; r < 4; ++r) {
      float mx = fmaxf(fmaxf(s[0][r], s[1][r]), fmaxf(s[2][r], s[3][r]));
      mx = fmaxf(mx, __shfl_xor(mx, 1));
      mx = fmaxf(mx, __shfl_xor(mx, 2));
      mx = fmaxf(mx, __shfl_xor(mx, 4));
      mx = fmaxf(mx, __shfl_xor(mx, 8));
      const float mnew = fmaxf(m_[r], mx);
      const float alpha = __expf(m_[r] - mnew);
      float sum = 0.f;
#pragma unroll
      for (int cc = 0; cc < 4; ++cc) {
        const float p = __expf(s[cc][r] - mnew);
        s[cc][r] = p;
        sum += p;
      }
      sum += __shfl_xor(sum, 1);
      sum += __shfl_xor(sum, 2);
      sum += __shfl_xor(sum, 4);
      sum += __shfl_xor(sum, 8);
      l_[r] = l_[r] * alpha + sum;
      m_[r] = mnew;
#pragma unroll
      for (int nb = 0; nb < 4; ++nb) oacc[nb][r] *= alpha;
#pragma unroll
      for (int cc = 0; cc < 4; ++cc)
        Pl[wv][(lg * 4 + r) * PSTR + cc * 16 + lr] = f2bf(s[cc][r]);
    }

    const bf16x8_t pa0 = *(const bf16x8_t*)&Pl[wv][lr * PSTR + lg * 8];
    const bf16x8_t pa1 = *(const bf16x8_t*)&Pl[wv][lr * PSTR + 32 + lg * 8];
#pragma unroll
    for (int nb = 0; nb < 4; ++nb) {
      const ushort* vb = &Vt[(nb * 16 + lr) * KSTR + lg * 8];
      const bf16x8_t vf0 = *(const bf16x8_t*)vb;
      const bf16x8_t vf1 = *(const bf16x8_t*)(vb + 32);
      oacc[nb] = __builtin_amdgcn_mfma_f32_16x16x32_bf16(pa0, vf0, oacc[nb], 0, 0, 0);
      oacc[nb] = __builtin_amdgcn_mfma_f32_16x16x32_bf16(pa1, vf1, oacc[nb], 0, 0, 0);
    }
  }

#pragma unroll
  for (int nb = 0; nb < 4; ++nb) {
#pragma unroll
    for (int r = 0; r < 4; ++r) {
      const int row = lg * 4 + r;
      const int col = nb * 16 + lr;
      O[((size_t)(b * kT + q0 + wv * 16 + row)) * kD + h * kHD + col] = f2bf(oacc[nb][r] / l_[r]);
    }
  }
}

// ---------- positional encoding add (f32 + bf16 copy) ----------
__global__ __launch_bounds__(256) void posenc_kernel(float* __restrict__ X, ushort* __restrict__ Xb)
{
  const int bt = blockIdx.x;
  const int t = bt & (kT - 1);
  float* row = X + (size_t)bt * kD;
  ushort* rb = Xb + (size_t)bt * kD;
#pragma unroll
  for (int p = 0; p < 2; ++p) {
    const int d = threadIdx.x + p * 256;
    const int j = d >> 1;
    const float inv = expf(-(float)j * 0.03597789207803197f);  // ln(10000)/256
    const float ang = (float)t * inv;
    const float pe = (d & 1) ? cosf(ang) : sinf(ang);
    const float v = row[d] + pe;
    row[d] = v;
    rb[d] = f2bf(v);
  }
}

// ---------- fused avgpool + im2col (bf16 out) ----------
__global__ void im2col_pool_kernel(const float* __restrict__ X, ushort* __restrict__ X5,
                                   int Tt, int n4)
{
  const int idx = blockIdx.x * 256 + threadIdx.x;
  if (idx >= n4) return;
  const int ci4 = idx & 127;
  int r = idx >> 7;
  const int tap = r % 5; r /= 5;
  const int t = r % Tt;
  const int b = r / Tt;
  const int ts = t + tap - 2;
  u16x4_t o = (u16x4_t){0, 0, 0, 0};
  if (ts >= 0 && ts < Tt) {
    const float* p = X + ((size_t)(b * 2 * Tt + 2 * ts)) * kD + ci4 * 4;
    const float4 x0 = *(const float4*)p;
    const float4 x1 = *(const float4*)(p + kD);
    o[0] = f2bf(0.5f * (x0.x + x1.x)); o[1] = f2bf(0.5f * (x0.y + x1.y));
    o[2] = f2bf(0.5f * (x0.z + x1.z)); o[3] = f2bf(0.5f * (x0.w + x1.w));
  }
  *(u16x4_t*)&X5[((size_t)(b * Tt + t)) * 2560 + tap * kD + ci4 * 4] = o;
}

// conv weight transpose -> bf16: Wt[co][tap*512+ci] = w[co][ci][tap]
__global__ void convw_t_kernel(const float* __restrict__ w, ushort* __restrict__ Wt)
{
  const int idx = blockIdx.x * 256 + threadIdx.x;
  if (idx >= 512 * 512 * 5) return;
  const int ci = idx & 511;
  int r = idx >> 9;
  const int tap = r % 5;
  const int co = r / 5;
  Wt[(size_t)co * 2560 + tap * 512 + ci] = f2bf(w[(size_t)co * 2560 + ci * 5 + tap]);
}

extern "C" void kernel_launch(void* const* d_in, const int* in_sizes, int n_in,
                              void* d_out, int out_size, void* d_ws, size_t ws_size,
                              hipStream_t stream)
{
  (void)in_sizes; (void)n_in; (void)out_size;
  const float* poses  = (const float*)d_in[0];
  const float* pose_w = (const float*)d_in[1];
  const float* pose_b = (const float*)d_in[2];
  const float* in_w   = (const float*)d_in[3];
  const float* in_b   = (const float*)d_in[4];
  const float* out_w  = (const float*)d_in[5];
  const float* out_b  = (const float*)d_in[6];
  const float* ln1_g  = (const float*)d_in[7];
  const float* ln1_b  = (const float*)d_in[8];
  const float* ffn_w1 = (const float*)d_in[9];
  const float* ffn_b1 = (const float*)d_in[10];
  const float* ffn_w2 = (const float*)d_in[11];
  const float* ffn_b2 = (const float*)d_in[12];
  const float* ln2_g  = (const float*)d_in[13];
  const float* ln2_b  = (const float*)d_in[14];
  const float* tcn1_w = (const float*)d_in[15];
  const float* tcn1_b = (const float*)d_in[16];
  const float* tcn2_w = (const float*)d_in[17];
  const float* tcn2_b = (const float*)d_in[18];
  const float* fc1_w  = (const float*)d_in[19];
  const float* fc1_b  = (const float*)d_in[20];
  const float* fc2_w  = (const float*)d_in[21];
  const float* fc2_b  = (const float*)d_in[22];

  // ---- workspace layout (byte offsets) ----
  char* base = (char*)d_ws;
  float*  A    = (float*)(base);
  float*  Y    = (float*)(base + 8388608);
  float*  P    = (float*)(base + 16777216);
  ushort* Abf  = (ushort*)(base + 25165824);
  ushort* QKV  = (ushort*)(base + 29360128);   // 6M ushort
  ushort* Ybf  = QKV;                          // lifetime-disjoint alias
  ushort* X5   = QKV;                          // head phase
  ushort* MID  = (ushort*)(base + 41943040);   // 8M ushort
  ushort* ATTb = MID;                          // lifetime-disjoint alias
  ushort* CW   = MID;                          // head phase
  ushort* Wbf  = (ushort*)(base + 58720256);

  // per-layer weight element counts
  const size_t nWq = (size_t)3 * kD * kD;      // 786432
  const size_t nWo = (size_t)kD * kD;          // 262144
  const size_t nW1 = (size_t)kFF * kD;         // 1048576
  const size_t nW2 = (size_t)kD * kFF;         // 1048576
  const size_t nWl = nWq + nWo + nW1 + nW2;    // 3145728
  const bool fullW = ws_size >= (size_t)58720256 + nWl * 8 * 2;

  const int M = kB * kT;  // 4096
  dim3 blk(256);
  dim3 blk512(512);
  auto cvt = [&](const float* s, ushort* d, size_t n) {
    cvt_kernel<<<(int)((n / 8 + 255) / 256), blk, 0, stream>>>(s, d, (int)(n / 8));
  };

  if (fullW) {   // one-time per launch: convert all transformer weights
    cvt(in_w,   Wbf,                        nWq * 8);
    cvt(out_w,  Wbf + nWq * 8,              nWo * 8);
    cvt(ffn_w1, Wbf + nWq * 8 + nWo * 8,    nW1 * 8);
    cvt(ffn_w2, Wbf + (nWq + nWo + nW1) * 8, nW2 * 8);
  }

  // embed: A = poses @ pose_w.T + pose_b ; += posenc (writes A + Abf)
  gemm_kernel<<<dim3(kD / GBN, M / GBM), blk, 0, stream>>>(poses, pose_w, pose_b, nullptr, A, M, kD, kIn, 0);
  posenc_kernel<<<M, blk, 0, stream>>>(A, Abf);

  for (int l = 0; l < 8; ++l) {
    const ushort *Wq, *Wo, *W1, *W2;
    if (fullW) {
      Wq = Wbf + (size_t)l * nWq;
      Wo = Wbf + nWq * 8 + (size_t)l * nWo;
      W1 = Wbf + nWq * 8 + nWo * 8 + (size_t)l * nW1;
      W2 = Wbf + (nWq + nWo + nW1) * 8 + (size_t)l * nW2;
    } else {   // rotate: convert this layer's weights into Wbf
      cvt(in_w   + (size_t)l * nWq, Wbf, nWq);
      cvt(out_w  + (size_t)l * nWo, Wbf + nWq, nWo);
      cvt(ffn_w1 + (size_t)l * nW1, Wbf + nWq + nWo, nW1);
      cvt(ffn_w2 + (size_t)l * nW2, Wbf + nWq + nWo + nW1, nW2);
      Wq = Wbf; Wo = Wbf + nWq; W1 = Wbf + nWq + nWo; W2 = Wbf + nWq + nWo + nW1;
    }

    // qkv: 128x128 tile, 8 waves
    bgemm_kernel<4, 2, 2, 4><<<dim3(3 * kD / 128, M / 128), blk512, 0, stream>>>(
        Abf, Wq, in_b + (size_t)l * 3 * kD, nullptr, nullptr, QKV, M, 3 * kD, kD, 0);
    // attention (bf16 in/out)
    attn_mfma_kernel<<<dim3(kT / 64, kH, kB), blk, 0, stream>>>(QKV, ATTb);
    // out-proj: Y = ATTb @ Wo + b + A (f32 out), 128x64 tile, 8 waves
    bgemm_kernel<2, 2, 4, 2><<<dim3(kD / 64, M / 128), blk512, 0, stream>>>(
        ATTb, Wo, out_b + (size_t)l * kD, A, Y, nullptr, M, kD, kD, 0);
    ln_kernel<<<M, blk, 0, stream>>>(Y, Ybf, ln1_g + (size_t)l * kD, ln1_b + (size_t)l * kD,
                                     nullptr, nullptr);
    // ffn1: MID = relu(Ybf @ W1 + b), 128x128 tile, 8 waves
    bgemm_kernel<4, 2, 2, 4><<<dim3(kFF / 128, M / 128), blk512, 0, stream>>>(
        Ybf, W1, ffn_b1 + (size_t)l * kFF, nullptr, nullptr, MID, M, kFF, kD, 1);
    // ffn2: A = MID @ W2 + b + Y (f32 out), 128x64 tile, 8 waves
    bgemm_kernel<2, 2, 4, 2><<<dim3(kD / 64, M / 128), blk512, 0, stream>>>(
        MID, W2, ffn_b2 + (size_t)l * kD, Y, A, nullptr, M, kD, kFF, 0);
    // ln2, fused with skip-stream: add P after LN (l=3,5,7), snapshot P (l=1,3,5)
    {
      const float* padd = (l == 3 || l == 5 || l == 7) ? P : nullptr;
      float* pout = (l == 1 || l == 3 || l == 5) ? P : nullptr;
      ln_kernel<<<M, blk, 0, stream>>>(A, Abf, ln2_g + (size_t)l * kD, ln2_b + (size_t)l * kD,
                                       padd, pout);
    }
  }

  // head: pool+conv1 -> pool+conv2 -> fc1 -> fc2
  {
    const int T1 = kT / 2;   // 512
    const int T2 = kT / 4;   // 256
    convw_t_kernel<<<(512 * 512 * 5 + 255) / 256, blk, 0, stream>>>(tcn1_w, CW);
    const int n4a = kB * T1 * 5 * (kD / 4);
    im2col_pool_kernel<<<(n4a + 255) / 256, blk, 0, stream>>>(A, X5, T1, n4a);
    // conv1 GEMM: M=2048, N=512, K=2560 -> 64x64 tile, 8 waves, 256 blocks
    bgemm_kernel<1, 2, 4, 2><<<dim3(kD / 64, kB * T1 / 64), blk512, 0, stream>>>(
        X5, CW, tcn1_b, nullptr, Y, nullptr, kB * T1, kD, 2560, 0);
    convw_t_kernel<<<(512 * 512 * 5 + 255) / 256, blk, 0, stream>>>(tcn2_w, CW);
    const int n4b = kB * T2 * 5 * (kD / 4);
    im2col_pool_kernel<<<(n4b + 255) / 256, blk, 0, stream>>>(Y, X5, T2, n4b);
    // conv2 GEMM: M=1024, N=512, K=2560
    bgemm_kernel<1, 2, 4, 2><<<dim3(kD / 64, kB * T2 / 64), blk512, 0, stream>>>(
        X5, CW, tcn2_b, nullptr, A, nullptr, kB * T2, kD, 2560, 0);
    const int Mh = kB * T2;  // 1024
    gemm_kernel<<<dim3(128 / GBN, Mh / GBM), blk, 0, stream>>>(A, fc1_w, fc1_b, nullptr, Y, Mh, 128, kD, 0);
    gemm_kernel<<<dim3((kNCLS + GBN - 1) / GBN, Mh / GBM), blk, 0, stream>>>(
        Y, fc2_w, fc2_b, nullptr, (float*)d_out, Mh, kNCLS, 128, 0);
  }
}

// Round 10
// 1261.638 us; speedup vs baseline: 1.2372x; 1.0156x over previous
//
#include <hip/hip_runtime.h>
#include <hip/hip_bf16.h>

static constexpr int kB = 4;
static constexpr int kT = 1024;
static constexpr int kIn = 172;
static constexpr int kD = 512;
static constexpr int kH = 8;
static constexpr int kHD = 64;
static constexpr int kFF = 2048;
static constexpr int kNCLS = 1296;
static constexpr float kEps = 1e-5f;

typedef __attribute__((ext_vector_type(8))) short bf16x8_t;
typedef __attribute__((ext_vector_type(4))) float f32x4_t;
typedef __attribute__((ext_vector_type(8))) unsigned short u16x8_t;
typedef __attribute__((ext_vector_type(4))) unsigned short u16x4_t;

// round-to-nearest-even f32 -> bf16 bits (finite inputs)
static __device__ __forceinline__ unsigned short f2bf(float f) {
  unsigned int u = __float_as_uint(f);
  unsigned int r = (u + 0x7fffu + ((u >> 16) & 1u)) >> 16;
  return (unsigned short)r;
}

// ---------- f32 -> bf16 bulk convert (n % 8 == 0) ----------
__global__ void cvt_kernel(const float* __restrict__ src, ushort* __restrict__ dst, int n8)
{
  const int i = blockIdx.x * 256 + threadIdx.x;
  if (i >= n8) return;
  const float4 a = *(const float4*)&src[i * 8];
  const float4 b = *(const float4*)&src[i * 8 + 4];
  u16x8_t t;
  t[0] = f2bf(a.x); t[1] = f2bf(a.y); t[2] = f2bf(a.z); t[3] = f2bf(a.w);
  t[4] = f2bf(b.x); t[5] = f2bf(b.y); t[6] = f2bf(b.z); t[7] = f2bf(b.w);
  *(u16x8_t*)&dst[i * 8] = t;
}

// ================= bf16 MFMA GEMM (8-wave, BK=64, reg-prefetch) =================
// C[m,n] = sum_k A[m,k]*W[n,k] + bias[n] (+relu) (+resid f32); C f32 and/or Cb bf16.
// WM x WN waves (block = WM*WN*64 threads); wave tile = MR*16 x NR*16;
// BM = MR*16*WM, BN = NR*16*WN, BK = 64. LDS rows padded to 72 ushorts (2-way banks).
// Requires M%BM==0, N%BN==0, K%64==0.
template<int MR, int NR, int WM, int WN>
__global__ __launch_bounds__(WM * WN * 64) void bgemm_kernel(
    const ushort* __restrict__ A, const ushort* __restrict__ W,
    const float* __restrict__ bias, const float* __restrict__ resid,
    float* __restrict__ C, ushort* __restrict__ Cb, int M, int N, int K, int doRelu)
{
  constexpr int THREADS = WM * WN * 64;
  constexpr int BM = MR * 16 * WM, BN = NR * 16 * WN;
  constexpr int SRD = 72;
  constexpr int TPRA = THREADS / BM, CSA = 64 / TPRA, NLA = CSA / 8;
  constexpr int TPRB = THREADS / BN, CSB = 64 / TPRB, NLB = CSB / 8;
  __shared__ ushort As[BM * SRD];
  __shared__ ushort Bs[BN * SRD];

  const int tid = threadIdx.x;
  int bid = blockIdx.y * gridDim.x + blockIdx.x;
  const int nwg = gridDim.x * gridDim.y;
  if ((nwg & 7) == 0) bid = (bid & 7) * (nwg >> 3) + (bid >> 3);   // XCD swizzle
  const int bm = (bid / gridDim.x) * BM, bn = (bid % gridDim.x) * BN;

  const int wv = tid >> 6, lane = tid & 63;
  const int lr = lane & 15, lg = lane >> 4;
  const int wr = wv / WN, wc = wv % WN;

  const int ra = tid / TPRA, ca = (tid % TPRA) * CSA;
  const int rb = tid / TPRB, cb = (tid % TPRB) * CSB;

  f32x4_t acc[MR][NR];
#pragma unroll
  for (int m = 0; m < MR; ++m)
#pragma unroll
    for (int n = 0; n < NR; ++n) acc[m][n] = (f32x4_t){0.f, 0.f, 0.f, 0.f};

  u16x8_t pa[NLA], pb[NLB];
  auto loadAB = [&](int k0) {
    const ushort* ap = A + (size_t)(bm + ra) * K + k0 + ca;
#pragma unroll
    for (int j = 0; j < NLA; ++j) pa[j] = *(const u16x8_t*)(ap + j * 8);
    const ushort* bp = W + (size_t)(bn + rb) * K + k0 + cb;
#pragma unroll
    for (int j = 0; j < NLB; ++j) pb[j] = *(const u16x8_t*)(bp + j * 8);
  };
  auto storeLDS = [&]() {
#pragma unroll
    for (int j = 0; j < NLA; ++j) *(u16x8_t*)&As[ra * SRD + ca + j * 8] = pa[j];
#pragma unroll
    for (int j = 0; j < NLB; ++j) *(u16x8_t*)&Bs[rb * SRD + cb + j * 8] = pb[j];
  };

  loadAB(0);
  storeLDS();
  __syncthreads();

  const int nsteps = K >> 6;
  for (int s = 0; s < nsteps; ++s) {
    const bool more = (s + 1) < nsteps;
    if (more) loadAB((s + 1) << 6);   // prefetch overlaps MFMA

#pragma unroll
    for (int kk = 0; kk < 2; ++kk) {
      bf16x8_t af[MR];
#pragma unroll
      for (int m = 0; m < MR; ++m)
        af[m] = *(const bf16x8_t*)&As[(wr * MR * 16 + m * 16 + lr) * SRD + kk * 32 + lg * 8];
#pragma unroll
      for (int n = 0; n < NR; ++n) {
        const bf16x8_t bf = *(const bf16x8_t*)&Bs[(wc * NR * 16 + n * 16 + lr) * SRD + kk * 32 + lg * 8];
#pragma unroll
        for (int m = 0; m < MR; ++m)
          acc[m][n] = __builtin_amdgcn_mfma_f32_16x16x32_bf16(af[m], bf, acc[m][n], 0, 0, 0);
      }
    }
    __syncthreads();
    if (more) { storeLDS(); __syncthreads(); }
  }

  // epilogue: D row = lg*4+v, col = lr (verified mapping)
#pragma unroll
  for (int m = 0; m < MR; ++m) {
#pragma unroll
    for (int v = 0; v < 4; ++v) {
      const int mm = bm + wr * MR * 16 + m * 16 + lg * 4 + v;
#pragma unroll
      for (int n = 0; n < NR; ++n) {
        const int nn = bn + wc * NR * 16 + n * 16 + lr;
        float val = acc[m][n][v] + bias[nn];
        if (doRelu) val = fmaxf(val, 0.f);
        if (resid) val += resid[(size_t)mm * N + nn];
        if (C)  C[(size_t)mm * N + nn] = val;
        if (Cb) Cb[(size_t)mm * N + nn] = f2bf(val);
      }
    }
  }
}

// ================= legacy f32 GEMM (embed K=172, fc1, fc2 N=1296) =================
#define GBM 64
#define GBN 64
#define GBK 16
#define LDST 68

__global__ __launch_bounds__(256) void gemm_kernel(
    const float* __restrict__ A, const float* __restrict__ W,
    const float* __restrict__ bias, const float* __restrict__ resid,
    float* __restrict__ C, int M, int N, int K, int doRelu)
{
  __shared__ __align__(16) float As[GBK][LDST];
  __shared__ __align__(16) float Ws[GBK][LDST];
  const int tid = threadIdx.x;
  const int bm = blockIdx.y * GBM;
  const int bn = blockIdx.x * GBN;
  const int tx = tid & 15, ty = tid >> 4;
  const int li = tid >> 2;
  const int lk = (tid & 3) << 2;

  float acc[4][4];
#pragma unroll
  for (int i = 0; i < 4; ++i)
#pragma unroll
    for (int j = 0; j < 4; ++j) acc[i][j] = 0.f;

  for (int k0 = 0; k0 < K; k0 += GBK) {
    float4 av = make_float4(0.f, 0.f, 0.f, 0.f);
    float4 wv = make_float4(0.f, 0.f, 0.f, 0.f);
    {
      const int m = bm + li;
      if (m < M) {
        if (k0 + lk + 4 <= K) {
          av = *(const float4*)&A[(size_t)m * K + k0 + lk];
        } else {
          float t4[4] = {0.f, 0.f, 0.f, 0.f};
          for (int c = 0; c < 4; ++c) { int k = k0 + lk + c; if (k < K) t4[c] = A[(size_t)m * K + k]; }
          av = make_float4(t4[0], t4[1], t4[2], t4[3]);
        }
      }
      const int n = bn + li;
      if (n < N) {
        if (k0 + lk + 4 <= K) {
          wv = *(const float4*)&W[(size_t)n * K + k0 + lk];
        } else {
          float t4[4] = {0.f, 0.f, 0.f, 0.f};
          for (int c = 0; c < 4; ++c) { int k = k0 + lk + c; if (k < K) t4[c] = W[(size_t)n * K + k]; }
          wv = make_float4(t4[0], t4[1], t4[2], t4[3]);
        }
      }
    }
    __syncthreads();
    As[lk + 0][li] = av.x; As[lk + 1][li] = av.y; As[lk + 2][li] = av.z; As[lk + 3][li] = av.w;
    Ws[lk + 0][li] = wv.x; Ws[lk + 1][li] = wv.y; Ws[lk + 2][li] = wv.z; Ws[lk + 3][li] = wv.w;
    __syncthreads();
#pragma unroll
    for (int kk = 0; kk < GBK; ++kk) {
      const float4 a4 = *(const float4*)&As[kk][ty << 2];
      const float4 b4 = *(const float4*)&Ws[kk][tx << 2];
      const float a[4] = {a4.x, a4.y, a4.z, a4.w};
      const float b[4] = {b4.x, b4.y, b4.z, b4.w};
#pragma unroll
      for (int i = 0; i < 4; ++i)
#pragma unroll
        for (int j = 0; j < 4; ++j) acc[i][j] = fmaf(a[i], b[j], acc[i][j]);
    }
  }

#pragma unroll
  for (int i = 0; i < 4; ++i) {
    const int m = bm + (ty << 2) + i;
    if (m >= M) continue;
#pragma unroll
    for (int j = 0; j < 4; ++j) {
      const int n = bn + (tx << 2) + j;
      if (n >= N) continue;
      float v = acc[i][j] + bias[n];
      if (doRelu) v = fmaxf(v, 0.f);
      if (resid) v += resid[(size_t)m * N + n];
      C[(size_t)m * N + n] = v;
    }
  }
}

// ---------- LayerNorm (f32 in-place + bf16 copy, optional skip-add/skip-save) ----------
__global__ __launch_bounds__(256) void ln_kernel(
    float* __restrict__ X, ushort* __restrict__ Xb,
    const float* __restrict__ g, const float* __restrict__ bta,
    const float* Padd, float* Pout)
{
  const int row = blockIdx.x;
  const int tid = threadIdx.x;
  float* xr = X + (size_t)row * kD;
  const float x0 = xr[tid];
  const float x1 = xr[tid + 256];
  float s = x0 + x1;
  float q = x0 * x0 + x1 * x1;
#pragma unroll
  for (int off = 32; off > 0; off >>= 1) {
    s += __shfl_down(s, off);
    q += __shfl_down(q, off);
  }
  __shared__ float ss[4], qq[4];
  const int w = tid >> 6;
  if ((tid & 63) == 0) { ss[w] = s; qq[w] = q; }
  __syncthreads();
  const float S = ss[0] + ss[1] + ss[2] + ss[3];
  const float Q = qq[0] + qq[1] + qq[2] + qq[3];
  const float mean = S * (1.f / kD);
  const float var = Q * (1.f / kD) - mean * mean;
  const float inv = rsqrtf(var + kEps);
  float v0 = (x0 - mean) * inv * g[tid] + bta[tid];
  float v1 = (x1 - mean) * inv * g[tid + 256] + bta[tid + 256];
  if (Padd) {
    v0 += Padd[(size_t)row * kD + tid];
    v1 += Padd[(size_t)row * kD + tid + 256];
  }
  xr[tid] = v0; xr[tid + 256] = v1;
  ushort* xb = Xb + (size_t)row * kD;
  xb[tid] = f2bf(v0); xb[tid + 256] = f2bf(v1);
  if (Pout) {
    Pout[(size_t)row * kD + tid] = v0;
    Pout[(size_t)row * kD + tid + 256] = v1;
  }
}

// ---------- MFMA flash attention (bf16 qkv in/out, f32 softmax/accum) ----------
// Double-buffered K/V LDS: ONE barrier per tile (writes at tile t touch only
// buf^1, which no wave reads after barrier(t-1)). 2-deep async staging: regs
// for tile t+2 issue before compute of t+1. Defer-max (THR=8): skip the
// alpha-rescale unless some row's max grew >8 (wave-uniform __any vote).
#define KSTR 72   // K/V LDS row stride (ushort)
#define PSTR 74   // P LDS row stride (odd dword stride -> ~2-way write banks)
__global__ __launch_bounds__(256) void attn_mfma_kernel(
    const ushort* __restrict__ qkv, ushort* __restrict__ O)
{
  const int b = blockIdx.z, h = blockIdx.y;
  const int q0 = blockIdx.x << 6;
  const int tid = threadIdx.x;
  const int wv = tid >> 6, lane = tid & 63;
  const int lr = lane & 15;
  const int lg = lane >> 4;

  __shared__ ushort Ks[2][64 * KSTR];
  __shared__ ushort Vt[2][64 * KSTR];
  __shared__ ushort Pl[4][16 * PSTR];

  bf16x8_t qa[2];
  {
    const ushort* qrow = qkv + ((size_t)(b * kT + q0 + wv * 16 + lr)) * (3 * kD) + h * kHD + lg * 8;
    qa[0] = *(const bf16x8_t*)qrow;
    qa[1] = *(const bf16x8_t*)(qrow + 32);
  }

  float m_[4], l_[4];
  f32x4_t oacc[4];
#pragma unroll
  for (int r = 0; r < 4; ++r) { m_[r] = -1e30f; l_[r] = 0.f; }
#pragma unroll
  for (int nb = 0; nb < 4; ++nb) oacc[nb] = (f32x4_t){0.f, 0.f, 0.f, 0.f};

  const int srow = tid >> 2;          // K staging: key row 0..63
  const int sd   = (tid & 3) << 4;    // K staging: d offset 0,16,32,48
  const int vkp  = tid & 31;          // V staging: key pair (keys 2vkp, 2vkp+1)
  const int vdh  = tid >> 5;          // V staging: d octet

  constexpr int NT = kT / 64;
  const size_t tstride = (size_t)64 * 3 * kD;
  const ushort* kptr = qkv + ((size_t)(b * kT + srow)) * (3 * kD) + kD + h * kHD + sd;
  const ushort* vptr = qkv + ((size_t)(b * kT + 2 * vkp)) * (3 * kD) + 2 * kD + h * kHD + vdh * 8;

  u16x8_t k0_, k1_, v0_, v1_;
  auto load_regs = [&]() {
    k0_ = *(const u16x8_t*)kptr;
    k1_ = *(const u16x8_t*)(kptr + 8);
    v0_ = *(const u16x8_t*)vptr;
    v1_ = *(const u16x8_t*)(vptr + 3 * kD);
    kptr += tstride; vptr += tstride;
  };
  auto write_lds = [&](int buf) {
    *(u16x8_t*)&Ks[buf][srow * KSTR + sd]     = k0_;
    *(u16x8_t*)&Ks[buf][srow * KSTR + sd + 8] = k1_;
#pragma unroll
    for (int e = 0; e < 8; ++e) {
      const unsigned int packv = (unsigned int)v0_[e] | ((unsigned int)v1_[e] << 16);
      *(unsigned int*)&Vt[buf][(vdh * 8 + e) * KSTR + 2 * vkp] = packv;
    }
  };

  load_regs();
  write_lds(0);
  __syncthreads();
  load_regs();   // tile 1 regs, in flight across tile 0 compute

  for (int kt = 0; kt < NT; ++kt) {
    const int buf = kt & 1;

    // QK^T from Ks[buf]
    f32x4_t s[4];
#pragma unroll
    for (int cc = 0; cc < 4; ++cc) {
      const ushort* kb = &Ks[buf][(cc * 16 + lr) * KSTR + lg * 8];
      const bf16x8_t kf0 = *(const bf16x8_t*)kb;
      const bf16x8_t kf1 = *(const bf16x8_t*)(kb + 32);
      f32x4_t acc = (f32x4_t){0.f, 0.f, 0.f, 0.f};
      acc = __builtin_amdgcn_mfma_f32_16x16x32_bf16(qa[0], kf0, acc, 0, 0, 0);
      acc = __builtin_amdgcn_mfma_f32_16x16x32_bf16(qa[1], kf1, acc, 0, 0, 0);
#pragma unroll
      for (int r = 0; r < 4; ++r) acc[r] *= 0.125f;
      s[cc] = acc;
    }

    // row maxes + defer-max vote
    float mx[4];
    int need = 0;
#pragma unroll
    for (int r = 0; r < 4; ++r) {
      float m2 = fmaxf(fmaxf(s[0][r], s[1][r]), fmaxf(s[2][r], s[3][r]));
      m2 = fmaxf(m2, __shfl_xor(m2, 1));
      m2 = fmaxf(m2, __shfl_xor(m2, 2));
      m2 = fmaxf(m2, __shfl_xor(m2, 4));
      m2 = fmaxf(m2, __shfl_xor(m2, 8));
      mx[r] = m2;
      if (m2 > m_[r] + 8.f) need = 1;
    }
    if (__any(need)) {   // wave-uniform (mx, m_ uniform per 16-lane row group)
#pragma unroll
      for (int r = 0; r < 4; ++r) {
        const float mnew = fmaxf(m_[r], mx[r]);
        const float alpha = __expf(m_[r] - mnew);   // 0 on first tile
        l_[r] *= alpha;
#pragma unroll
        for (int nb = 0; nb < 4; ++nb) oacc[nb][r] *= alpha;
        m_[r] = mnew;
      }
    }
#pragma unroll
    for (int r = 0; r < 4; ++r) {
      float sum = 0.f;
#pragma unroll
      for (int cc = 0; cc < 4; ++cc) {
        const float p = __expf(s[cc][r] - m_[r]);   // bounded by e^8
        s[cc][r] = p;
        sum += p;
      }
      sum += __shfl_xor(sum, 1);
      sum += __shfl_xor(sum, 2);
      sum += __shfl_xor(sum, 4);
      sum += __shfl_xor(sum, 8);
      l_[r] += sum;
#pragma unroll
      for (int cc = 0; cc < 4; ++cc)
        Pl[wv][(lg * 4 + r) * PSTR + cc * 16 + lr] = f2bf(s[cc][r]);
    }

    // PV from Vt[buf] (Pl is wave-private; lgkmcnt ordering suffices)
    const bf16x8_t pa0 = *(const bf16x8_t*)&Pl[wv][lr * PSTR + lg * 8];
    const bf16x8_t pa1 = *(const bf16x8_t*)&Pl[wv][lr * PSTR + 32 + lg * 8];
#pragma unroll
    for (int nb = 0; nb < 4; ++nb) {
      const ushort* vb = &Vt[buf][(nb * 16 + lr) * KSTR + lg * 8];
      const bf16x8_t vf0 = *(const bf16x8_t*)vb;
      const bf16x8_t vf1 = *(const bf16x8_t*)(vb + 32);
      oacc[nb] = __builtin_amdgcn_mfma_f32_16x16x32_bf16(pa0, vf0, oacc[nb], 0, 0, 0);
      oacc[nb] = __builtin_amdgcn_mfma_f32_16x16x32_bf16(pa1, vf1, oacc[nb], 0, 0, 0);
    }

    if (kt + 1 < NT) {
      write_lds(buf ^ 1);              // regs for kt+1 (vmcnt-waited here)
      if (kt + 2 < NT) load_regs();    // issue kt+2 loads; hide under kt+1
    }
    __syncthreads();                   // single barrier per tile
  }

#pragma unroll
  for (int nb = 0; nb < 4; ++nb) {
#pragma unroll
    for (int r = 0; r < 4; ++r) {
      const int row = lg * 4 + r;
      const int col = nb * 16 + lr;
      O[((size_t)(b * kT + q0 + wv * 16 + row)) * kD + h * kHD + col] = f2bf(oacc[nb][r] / l_[r]);
    }
  }
}

// ---------- positional encoding add (f32 + bf16 copy) ----------
__global__ __launch_bounds__(256) void posenc_kernel(float* __restrict__ X, ushort* __restrict__ Xb)
{
  const int bt = blockIdx.x;
  const int t = bt & (kT - 1);
  float* row = X + (size_t)bt * kD;
  ushort* rb = Xb + (size_t)bt * kD;
#pragma unroll
  for (int p = 0; p < 2; ++p) {
    const int d = threadIdx.x + p * 256;
    const int j = d >> 1;
    const float inv = expf(-(float)j * 0.03597789207803197f);  // ln(10000)/256
    const float ang = (float)t * inv;
    const float pe = (d & 1) ? cosf(ang) : sinf(ang);
    const float v = row[d] + pe;
    row[d] = v;
    rb[d] = f2bf(v);
  }
}

// ---------- fused avgpool + im2col (bf16 out) ----------
__global__ void im2col_pool_kernel(const float* __restrict__ X, ushort* __restrict__ X5,
                                   int Tt, int n4)
{
  const int idx = blockIdx.x * 256 + threadIdx.x;
  if (idx >= n4) return;
  const int ci4 = idx & 127;
  int r = idx >> 7;
  const int tap = r % 5; r /= 5;
  const int t = r % Tt;
  const int b = r / Tt;
  const int ts = t + tap - 2;
  u16x4_t o = (u16x4_t){0, 0, 0, 0};
  if (ts >= 0 && ts < Tt) {
    const float* p = X + ((size_t)(b * 2 * Tt + 2 * ts)) * kD + ci4 * 4;
    const float4 x0 = *(const float4*)p;
    const float4 x1 = *(const float4*)(p + kD);
    o[0] = f2bf(0.5f * (x0.x + x1.x)); o[1] = f2bf(0.5f * (x0.y + x1.y));
    o[2] = f2bf(0.5f * (x0.z + x1.z)); o[3] = f2bf(0.5f * (x0.w + x1.w));
  }
  *(u16x4_t*)&X5[((size_t)(b * Tt + t)) * 2560 + tap * kD + ci4 * 4] = o;
}

// conv weight transpose -> bf16: Wt[co][tap*512+ci] = w[co][ci][tap]
__global__ void convw_t_kernel(const float* __restrict__ w, ushort* __restrict__ Wt)
{
  const int idx = blockIdx.x * 256 + threadIdx.x;
  if (idx >= 512 * 512 * 5) return;
  const int ci = idx & 511;
  int r = idx >> 9;
  const int tap = r % 5;
  const int co = r / 5;
  Wt[(size_t)co * 2560 + tap * 512 + ci] = f2bf(w[(size_t)co * 2560 + ci * 5 + tap]);
}

extern "C" void kernel_launch(void* const* d_in, const int* in_sizes, int n_in,
                              void* d_out, int out_size, void* d_ws, size_t ws_size,
                              hipStream_t stream)
{
  (void)in_sizes; (void)n_in; (void)out_size;
  const float* poses  = (const float*)d_in[0];
  const float* pose_w = (const float*)d_in[1];
  const float* pose_b = (const float*)d_in[2];
  const float* in_w   = (const float*)d_in[3];
  const float* in_b   = (const float*)d_in[4];
  const float* out_w  = (const float*)d_in[5];
  const float* out_b  = (const float*)d_in[6];
  const float* ln1_g  = (const float*)d_in[7];
  const float* ln1_b  = (const float*)d_in[8];
  const float* ffn_w1 = (const float*)d_in[9];
  const float* ffn_b1 = (const float*)d_in[10];
  const float* ffn_w2 = (const float*)d_in[11];
  const float* ffn_b2 = (const float*)d_in[12];
  const float* ln2_g  = (const float*)d_in[13];
  const float* ln2_b  = (const float*)d_in[14];
  const float* tcn1_w = (const float*)d_in[15];
  const float* tcn1_b = (const float*)d_in[16];
  const float* tcn2_w = (const float*)d_in[17];
  const float* tcn2_b = (const float*)d_in[18];
  const float* fc1_w  = (const float*)d_in[19];
  const float* fc1_b  = (const float*)d_in[20];
  const float* fc2_w  = (const float*)d_in[21];
  const float* fc2_b  = (const float*)d_in[22];

  // ---- workspace layout (byte offsets) ----
  char* base = (char*)d_ws;
  float*  A    = (float*)(base);
  float*  Y    = (float*)(base + 8388608);
  float*  P    = (float*)(base + 16777216);
  ushort* Abf  = (ushort*)(base + 25165824);
  ushort* QKV  = (ushort*)(base + 29360128);   // 6M ushort
  ushort* Ybf  = QKV;                          // lifetime-disjoint alias
  ushort* X5   = QKV;                          // head phase
  ushort* MID  = (ushort*)(base + 41943040);   // 8M ushort
  ushort* ATTb = MID;                          // lifetime-disjoint alias
  ushort* CW   = MID;                          // head phase
  ushort* Wbf  = (ushort*)(base + 58720256);

  // per-layer weight element counts
  const size_t nWq = (size_t)3 * kD * kD;      // 786432
  const size_t nWo = (size_t)kD * kD;          // 262144
  const size_t nW1 = (size_t)kFF * kD;         // 1048576
  const size_t nW2 = (size_t)kD * kFF;         // 1048576
  const size_t nWl = nWq + nWo + nW1 + nW2;    // 3145728
  const bool fullW = ws_size >= (size_t)58720256 + nWl * 8 * 2;

  const int M = kB * kT;  // 4096
  dim3 blk(256);
  dim3 blk512(512);
  auto cvt = [&](const float* s, ushort* d, size_t n) {
    cvt_kernel<<<(int)((n / 8 + 255) / 256), blk, 0, stream>>>(s, d, (int)(n / 8));
  };

  if (fullW) {   // one-time per launch: convert all transformer weights
    cvt(in_w,   Wbf,                        nWq * 8);
    cvt(out_w,  Wbf + nWq * 8,              nWo * 8);
    cvt(ffn_w1, Wbf + nWq * 8 + nWo * 8,    nW1 * 8);
    cvt(ffn_w2, Wbf + (nWq + nWo + nW1) * 8, nW2 * 8);
  }

  // embed: A = poses @ pose_w.T + pose_b ; += posenc (writes A + Abf)
  gemm_kernel<<<dim3(kD / GBN, M / GBM), blk, 0, stream>>>(poses, pose_w, pose_b, nullptr, A, M, kD, kIn, 0);
  posenc_kernel<<<M, blk, 0, stream>>>(A, Abf);

  for (int l = 0; l < 8; ++l) {
    const ushort *Wq, *Wo, *W1, *W2;
    if (fullW) {
      Wq = Wbf + (size_t)l * nWq;
      Wo = Wbf + nWq * 8 + (size_t)l * nWo;
      W1 = Wbf + nWq * 8 + nWo * 8 + (size_t)l * nW1;
      W2 = Wbf + (nWq + nWo + nW1) * 8 + (size_t)l * nW2;
    } else {   // rotate: convert this layer's weights into Wbf
      cvt(in_w   + (size_t)l * nWq, Wbf, nWq);
      cvt(out_w  + (size_t)l * nWo, Wbf + nWq, nWo);
      cvt(ffn_w1 + (size_t)l * nW1, Wbf + nWq + nWo, nW1);
      cvt(ffn_w2 + (size_t)l * nW2, Wbf + nWq + nWo + nW1, nW2);
      Wq = Wbf; Wo = Wbf + nWq; W1 = Wbf + nWq + nWo; W2 = Wbf + nWq + nWo + nW1;
    }

    // qkv: 128x128 tile, 8 waves
    bgemm_kernel<4, 2, 2, 4><<<dim3(3 * kD / 128, M / 128), blk512, 0, stream>>>(
        Abf, Wq, in_b + (size_t)l * 3 * kD, nullptr, nullptr, QKV, M, 3 * kD, kD, 0);
    // attention (bf16 in/out)
    attn_mfma_kernel<<<dim3(kT / 64, kH, kB), blk, 0, stream>>>(QKV, ATTb);
    // out-proj: Y = ATTb @ Wo + b + A (f32 out), 128x64 tile, 8 waves
    bgemm_kernel<2, 2, 4, 2><<<dim3(kD / 64, M / 128), blk512, 0, stream>>>(
        ATTb, Wo, out_b + (size_t)l * kD, A, Y, nullptr, M, kD, kD, 0);
    ln_kernel<<<M, blk, 0, stream>>>(Y, Ybf, ln1_g + (size_t)l * kD, ln1_b + (size_t)l * kD,
                                     nullptr, nullptr);
    // ffn1: MID = relu(Ybf @ W1 + b), 128x128 tile, 8 waves
    bgemm_kernel<4, 2, 2, 4><<<dim3(kFF / 128, M / 128), blk512, 0, stream>>>(
        Ybf, W1, ffn_b1 + (size_t)l * kFF, nullptr, nullptr, MID, M, kFF, kD, 1);
    // ffn2: A = MID @ W2 + b + Y (f32 out), 128x64 tile, 8 waves
    bgemm_kernel<2, 2, 4, 2><<<dim3(kD / 64, M / 128), blk512, 0, stream>>>(
        MID, W2, ffn_b2 + (size_t)l * kD, Y, A, nullptr, M, kD, kFF, 0);
    // ln2, fused with skip-stream: add P after LN (l=3,5,7), snapshot P (l=1,3,5)
    {
      const float* padd = (l == 3 || l == 5 || l == 7) ? P : nullptr;
      float* pout = (l == 1 || l == 3 || l == 5) ? P : nullptr;
      ln_kernel<<<M, blk, 0, stream>>>(A, Abf, ln2_g + (size_t)l * kD, ln2_b + (size_t)l * kD,
                                       padd, pout);
    }
  }

  // head: pool+conv1 -> pool+conv2 -> fc1 -> fc2
  {
    const int T1 = kT / 2;   // 512
    const int T2 = kT / 4;   // 256
    convw_t_kernel<<<(512 * 512 * 5 + 255) / 256, blk, 0, stream>>>(tcn1_w, CW);
    const int n4a = kB * T1 * 5 * (kD / 4);
    im2col_pool_kernel<<<(n4a + 255) / 256, blk, 0, stream>>>(A, X5, T1, n4a);
    // conv1 GEMM: M=2048, N=512, K=2560 -> 64x64 tile, 8 waves, 256 blocks
    bgemm_kernel<1, 2, 4, 2><<<dim3(kD / 64, kB * T1 / 64), blk512, 0, stream>>>(
        X5, CW, tcn1_b, nullptr, Y, nullptr, kB * T1, kD, 2560, 0);
    convw_t_kernel<<<(512 * 512 * 5 + 255) / 256, blk, 0, stream>>>(tcn2_w, CW);
    const int n4b = kB * T2 * 5 * (kD / 4);
    im2col_pool_kernel<<<(n4b + 255) / 256, blk, 0, stream>>>(Y, X5, T2, n4b);
    // conv2 GEMM: M=1024, N=512, K=2560
    bgemm_kernel<1, 2, 4, 2><<<dim3(kD / 64, kB * T2 / 64), blk512, 0, stream>>>(
        X5, CW, tcn2_b, nullptr, A, nullptr, kB * T2, kD, 2560, 0);
    const int Mh = kB * T2;  // 1024
    gemm_kernel<<<dim3(128 / GBN, Mh / GBM), blk, 0, stream>>>(A, fc1_w, fc1_b, nullptr, Y, Mh, 128, kD, 0);
    gemm_kernel<<<dim3((kNCLS + GBN - 1) / GBN, Mh / GBM), blk, 0, stream>>>(
        Y, fc2_w, fc2_b, nullptr, (float*)d_out, Mh, kNCLS, 128, 0);
  }
}